// Round 11
// baseline (240.204 us; speedup 1.0000x reference)
//
#include <hip/hip_runtime.h>

constexpr int N    = 50000;
constexpr int E    = 800000;
constexpr int CIN  = 128;
constexpr int COUT = 64;
constexpr float SELF_LOOP_W = 2.0f;

constexpr int NB     = (N + 63) / 64;   // 782 buckets of 64 nodes
constexpr int SUBCAP = 384;             // per-sub-cursor capacity (mean 256, +8 sigma)
constexpr int CAP    = 4 * SUBCAP;      // 1536 slots/bucket
constexpr int PBLK   = (E + 1023) / 1024;   // 782 blocks x 256 thr x 4 edges

typedef float          vfloat4  __attribute__((ext_vector_type(4)));
typedef int            vint2    __attribute__((ext_vector_type(2)));
typedef int            vint4    __attribute__((ext_vector_type(4)));
typedef unsigned short vushort4 __attribute__((ext_vector_type(4)));

// round-to-nearest-even fp32 -> bf16
__device__ __forceinline__ unsigned short f2bf(float f) {
    unsigned int u = __float_as_uint(f);
    u += 0x7FFFu + ((u >> 16) & 1u);
    return (unsigned short)(u >> 16);
}
__device__ __forceinline__ float bf2f(unsigned short h) {
    return __uint_as_float(((unsigned int)h) << 16);
}

// ---------------------------------------------------------------------------
// BARRIER-FREE partition: no LDS, no __syncthreads, no block histogram.
// Each record takes a slot via a returning global atomicAdd on one of 4
// per-bucket sub-cursors (spread by (t+u)&3); deg accumulates fire-and-forget.
// Each thread waits only on its own RMW returns (TLP-hideable), removing the
// convoy stalls that left R9's partition 99% idle.
__global__ __launch_bounds__(256) void partition_kernel(const int* __restrict__ row,
                                                        const int* __restrict__ col,
                                                        const float* __restrict__ ew,
                                                        int* __restrict__ bcur,
                                                        float* __restrict__ deg,
                                                        vint2* __restrict__ pk) {
    const int t = blockIdx.x * 256 + threadIdx.x;
    const int e = t * 4;
    if (e >= E) return;                 // E%4==0 -> whole int4 in-bounds

    vint4   c4 = *(const vint4*)(col + e);
    vint4   r4 = *(const vint4*)(row + e);
    vfloat4 w4 = *(const vfloat4*)(ew + e);

    #pragma unroll
    for (int u = 0; u < 4; ++u) {
        int c   = c4[u];
        int bkt = c >> 6;
        int sub = (threadIdx.x + u) & 3;
        int p   = atomicAdd(&bcur[bkt * 4 + sub], 1);
        if (p < SUBCAP) {               // capacity guard (mean 256, cap 384)
            vint2 v;
            v.x = r4[u] | ((c & 63) << 20);
            v.y = __float_as_int(w4[u]);
            pk[(size_t)bkt * CAP + sub * SUBCAP + p] = v;
        }
        atomicAdd(&deg[c], w4[u]);      // global f32, fire-and-forget
    }
}

// ---------------------------------------------------------------------------
// PURE GEMM: xwh = bf16(x @ W), 64x64 tile, 4x4/thread, b128 LDS reads.
// Epilogue: dinv[node] = rsqrtf(2 + deg[node]) (deg complete: stream order).
__global__ __launch_bounds__(256) void xw_kernel(const float* __restrict__ x,
                                                 const float* __restrict__ W,
                                                 const float* __restrict__ deg,
                                                 unsigned short* __restrict__ xwh,
                                                 float* __restrict__ dinv) {
    __shared__ __align__(16) float xs[64][132];   // row stride 528B

    const int t    = threadIdx.x;
    const int b    = blockIdx.x;
    const int base = b * 64;

    #pragma unroll
    for (int i = 0; i < 8; ++i) {
        int f4  = i * 256 + t;
        int r   = f4 >> 5;
        int c4  = f4 & 31;
        int node = base + r;
        if (node >= N) node = N - 1;
        *(vfloat4*)&xs[r][c4 * 4] = *(const vfloat4*)(x + (size_t)node * CIN + c4 * 4);
    }
    __syncthreads();

    // dinv epilogue issued early (independent of LDS)
    if (t < 64) {
        int node = base + t;
        if (node < N) dinv[node] = rsqrtf(SELF_LOOP_W + deg[node]);
    }

    const int tc = t & 15;
    const int tn = t >> 4;

    float acc[4][4];
    #pragma unroll
    for (int i = 0; i < 4; ++i)
        #pragma unroll
        for (int j = 0; j < 4; ++j) acc[i][j] = 0.f;

    const float* Wp = W + tc * 4;
    #pragma unroll 4
    for (int k = 0; k < CIN; k += 4) {
        vfloat4 b0 = *(const vfloat4*)(Wp + (size_t)(k + 0) * COUT);
        vfloat4 b1 = *(const vfloat4*)(Wp + (size_t)(k + 1) * COUT);
        vfloat4 b2 = *(const vfloat4*)(Wp + (size_t)(k + 2) * COUT);
        vfloat4 b3 = *(const vfloat4*)(Wp + (size_t)(k + 3) * COUT);
        #pragma unroll
        for (int i = 0; i < 4; ++i) {
            vfloat4 a = *(const vfloat4*)&xs[tn * 4 + i][k];   // ds_read_b128
            #pragma unroll
            for (int j = 0; j < 4; ++j)
                acc[i][j] += a[0] * b0[j] + a[1] * b1[j] + a[2] * b2[j] + a[3] * b3[j];
        }
    }

    #pragma unroll
    for (int i = 0; i < 4; ++i) {
        int node = base + tn * 4 + i;
        if (node >= N) continue;
        vushort4 hv;
        #pragma unroll
        for (int j = 0; j < 4; ++j) hv[j] = f2bf(acc[i][j]);
        *(vushort4*)(xwh + (size_t)node * COUT + tc * 4) = hv;
    }
}

// ---------------------------------------------------------------------------
// per-bucket: pk -> LDS counting-sort, then atomic-free per-node accumulation
// with QUARTER-WAVE pairing (R0-verified 27 us path). Only change: staging
// reads 4 sub-segments per bucket (sub-cursor layout).
__global__ __launch_bounds__(512) void aggregate_kernel(const int* __restrict__ bcur,
                                                        const vint2* __restrict__ pk,
                                                        const float* __restrict__ dinv,
                                                        const unsigned short* __restrict__ xwh,
                                                        const float* __restrict__ bias,
                                                        float* __restrict__ out) {
    __shared__ int   rawx[CAP];      // raw: row | ln<<20
    __shared__ float rawn[CAP];      // raw: ew * dinv[row]
    __shared__ int   s_r[CAP];       // sorted: row
    __shared__ float s_n[CAP];       // sorted: norm
    __shared__ int   lhist[64], lofs[64], lcur[64];

    const int t    = threadIdx.x;
    const int lane = t & 63;
    const int wv   = t >> 6;          // 0..7
    const int b    = blockIdx.x;
    const size_t base = (size_t)b * CAP;

    if (t < 64) lhist[t] = 0;
    __syncthreads();

    // stage + histogram from the 4 sub-segments (coalesced pk reads)
    int ofs = 0;
    #pragma unroll
    for (int s = 0; s < 4; ++s) {
        int cs = min(bcur[b * 4 + s], SUBCAP);
        for (int j = t; j < cs; j += 512) {
            vint2 v = pk[base + s * SUBCAP + j];
            rawx[ofs + j] = v.x;
            rawn[ofs + j] = __int_as_float(v.y) * dinv[v.x & 0xFFFFF];
            atomicAdd(&lhist[(v.x >> 20) & 63], 1);
        }
        ofs += cs;
    }
    const int cnt = ofs;
    __syncthreads();

    // wave 0: exclusive prefix scan of the 64 counters
    if (t < 64) {
        int v = lhist[t];
        int s = v;
        #pragma unroll
        for (int d = 1; d < 64; d <<= 1) {
            int u = __shfl_up(s, d);
            if (lane >= d) s += u;
        }
        lofs[t] = s - v;
        lcur[t] = s - v;
    }
    __syncthreads();

    // counting-sort scatter (LDS -> LDS)
    for (int j = t; j < cnt; j += 512) {
        int xv = rawx[j];
        int p  = atomicAdd(&lcur[(xv >> 20) & 63], 1);
        s_r[p] = xv & 0xFFFFF;
        s_n[p] = rawn[j];
    }
    __syncthreads();

    const int q  = lane >> 4;        // record quarter 0..3
    const int c4 = lane & 15;        // channel quad: channels c4*4 .. +3

    for (int nd = wv; nd < 64; nd += 8) {
        int node = b * 64 + nd;
        if (node >= N) continue;     // wave-uniform
        int s0 = lofs[nd];
        int e0 = s0 + lhist[nd];

        float a0 = 0.f, a1 = 0.f, a2 = 0.f, a3 = 0.f;
        for (int i = s0; i < e0; i += 16) {
            int rr[4]; float nn[4]; vushort4 vv[4];
            #pragma unroll
            for (int u = 0; u < 4; ++u) {
                int j = i + 4 * u + q;
                bool ok = (j < e0);
                rr[u] = ok ? s_r[j] : s_r[s0];
                nn[u] = ok ? s_n[j] : 0.f;
            }
            #pragma unroll
            for (int u = 0; u < 4; ++u)
                vv[u] = *(const vushort4*)(xwh + (size_t)rr[u] * COUT + c4 * 4);
            #pragma unroll
            for (int u = 0; u < 4; ++u) {
                a0 += nn[u] * bf2f(vv[u][0]);
                a1 += nn[u] * bf2f(vv[u][1]);
                a2 += nn[u] * bf2f(vv[u][2]);
                a3 += nn[u] * bf2f(vv[u][3]);
            }
        }
        // combine the four record-quarters
        a0 += __shfl_xor(a0, 16); a0 += __shfl_xor(a0, 32);
        a1 += __shfl_xor(a1, 16); a1 += __shfl_xor(a1, 32);
        a2 += __shfl_xor(a2, 16); a2 += __shfl_xor(a2, 32);
        a3 += __shfl_xor(a3, 16); a3 += __shfl_xor(a3, 32);

        if (q == 0) {                // lanes 0..15 write float4 (256B row)
            float dc = dinv[node];
            float s2 = SELF_LOOP_W * dc * dc;
            vushort4 sh = *(const vushort4*)(xwh + (size_t)node * COUT + c4 * 4);
            vfloat4  bv = *(const vfloat4*)(bias + c4 * 4);
            vfloat4  o;
            o[0] = dc * a0 + s2 * bf2f(sh[0]) + bv[0];
            o[1] = dc * a1 + s2 * bf2f(sh[1]) + bv[1];
            o[2] = dc * a2 + s2 * bf2f(sh[2]) + bv[2];
            o[3] = dc * a3 + s2 * bf2f(sh[3]) + bv[3];
            *(vfloat4*)(out + (size_t)node * COUT + c4 * 4) = o;
        }
    }
}

// ---------------------------------------------------------------------------
extern "C" void kernel_launch(void* const* d_in, const int* in_sizes, int n_in,
                              void* d_out, int out_size, void* d_ws, size_t ws_size,
                              hipStream_t stream) {
    const float* x  = (const float*)d_in[0];
    const int*   ei = (const int*)d_in[1];   // [2, E] int32
    const float* ew = (const float*)d_in[2];
    const float* W  = (const float*)d_in[3];
    const float* b  = (const float*)d_in[4];
    float* out = (float*)d_out;

    // ws layout: xwh | dinv | deg | bcur | pk   (all 8B-aligned offsets)
    unsigned short* xwh  = (unsigned short*)d_ws;            // N*COUT bf16 (6.4 MB)
    float*          dinv = (float*)(xwh + (size_t)N * COUT); // N floats
    float*          deg  = dinv + N;                         // N floats
    int*            bcur = (int*)(deg + N);                  // NB*4 ints
    vint2*          pk   = (vint2*)(bcur + NB * 4);          // NB*CAP records (9.6 MB)

    const int* rowp = ei;
    const int* colp = ei + E;

    // zero deg + bcur in one contiguous memset (~212 KB)
    hipMemsetAsync(deg, 0, (size_t)(N + NB * 4) * sizeof(int), stream);
    partition_kernel<<<PBLK, 256, 0, stream>>>(rowp, colp, ew, bcur, deg, pk);
    xw_kernel       <<<NB, 256, 0, stream>>>(x, W, deg, xwh, dinv);
    aggregate_kernel<<<NB, 512, 0, stream>>>(bcur, pk, dinv, xwh, b, out);
}

// Round 12
// 144.338 us; speedup vs baseline: 1.6642x; 1.6642x over previous
//
#include <hip/hip_runtime.h>

constexpr int N    = 50000;
constexpr int E    = 800000;
constexpr int CIN  = 128;
constexpr int COUT = 64;
constexpr float SELF_LOOP_W = 2.0f;

constexpr int NB   = (N + 63) / 64;   // 782 buckets of 64 nodes
constexpr int CAP  = 1536;            // slots/bucket (mean 1023, sigma 32)
constexpr int EPB  = 8192;            // edges per partition block (16/thread @512)
constexpr int PBLK = (E + EPB - 1) / EPB;   // 98 -> bcur chain depth 98 (was 391)

typedef float          vfloat4  __attribute__((ext_vector_type(4)));
typedef int            vint2    __attribute__((ext_vector_type(2)));
typedef int            vint4    __attribute__((ext_vector_type(4)));
typedef unsigned short vushort4 __attribute__((ext_vector_type(4)));

// round-to-nearest-even fp32 -> bf16
__device__ __forceinline__ unsigned short f2bf(float f) {
    unsigned int u = __float_as_uint(f);
    u += 0x7FFFu + ((u >> 16) & 1u);
    return (unsigned short)(u >> 16);
}
__device__ __forceinline__ float bf2f(unsigned short h) {
    return __uint_as_float(((unsigned int)h) << 16);
}

// ---------------------------------------------------------------------------
// two-pass radix partition, 3 barrier phases, 16 edges/thread (4 int4 groups).
// EPB=8192 -> 98 blocks -> per-cursor global-atomic chain depth 98 (was 391):
// single-variable test of the cursor-chain theory. Longer per-bucket runs
// (~12.6 records/block-bucket) also improve scatter-write line locality.
__global__ __launch_bounds__(512) void partition_kernel(const int* __restrict__ row,
                                                        const int* __restrict__ col,
                                                        const float* __restrict__ ew,
                                                        int* __restrict__ bcur,
                                                        vint2* __restrict__ pk) {
    __shared__ int lhist[NB];
    __shared__ int lbase[NB];
    const int t  = threadIdx.x;
    const int eb = blockIdx.x * EPB + t * 4;

    for (int i = t; i < NB; i += 512) lhist[i] = 0;
    __syncthreads();

    vint4 c4[4];
    #pragma unroll
    for (int g = 0; g < 4; ++g) {
        const int e = eb + g * 2048;
        if (e < E) {                    // E%4==0 -> whole int4 in-bounds
            c4[g] = *(const vint4*)(col + e);
            #pragma unroll
            for (int u = 0; u < 4; ++u) atomicAdd(&lhist[c4[g][u] >> 6], 1);
        }
    }
    __syncthreads();

    for (int i = t; i < NB; i += 512) {
        int h = lhist[i];
        if (h > 0) lbase[i] = i * CAP + atomicAdd(&bcur[i], h);
    }
    __syncthreads();

    #pragma unroll
    for (int g = 0; g < 4; ++g) {
        const int e = eb + g * 2048;
        if (e < E) {
            vint4   r4 = *(const vint4*)(row + e);
            vfloat4 w4 = *(const vfloat4*)(ew + e);
            #pragma unroll
            for (int u = 0; u < 4; ++u) {
                int c   = c4[g][u];
                int bkt = c >> 6;
                int p   = atomicAdd(&lbase[bkt], 1);
                if (p < (bkt + 1) * CAP) {     // capacity guard
                    vint2 v;
                    v.x = r4[u] | ((c & 63) << 20);
                    v.y = __float_as_int(w4[u]);
                    pk[p] = v;
                }
            }
        }
    }
}

// ---------------------------------------------------------------------------
// fused: xwh = bf16(x @ W) (64x64 tile, 4x4/thread, b128 LDS reads)
// THEN per-bucket deg->dinv (proven R0/R7 variant).
__global__ __launch_bounds__(256) void xw_deg_kernel(const float* __restrict__ x,
                                                     const float* __restrict__ W,
                                                     const int* __restrict__ bcur,
                                                     const vint2* __restrict__ pk,
                                                     unsigned short* __restrict__ xwh,
                                                     float* __restrict__ dinv) {
    __shared__ __align__(16) float xs[64][132];   // row stride 528B
    __shared__ float ldeg[64];

    const int t    = threadIdx.x;
    const int b    = blockIdx.x;
    const int base = b * 64;

    // ---- GEMM phase ----
    #pragma unroll
    for (int i = 0; i < 8; ++i) {
        int f4  = i * 256 + t;
        int r   = f4 >> 5;
        int c4  = f4 & 31;
        int node = base + r;
        if (node >= N) node = N - 1;
        vfloat4 v = *(const vfloat4*)(x + (size_t)node * CIN + c4 * 4);
        *(vfloat4*)&xs[r][c4 * 4] = v;
    }
    if (t < 64) ldeg[t] = 0.f;
    __syncthreads();

    const int tc = t & 15;
    const int tn = t >> 4;

    float acc[4][4];
    #pragma unroll
    for (int i = 0; i < 4; ++i)
        #pragma unroll
        for (int j = 0; j < 4; ++j) acc[i][j] = 0.f;

    const float* Wp = W + tc * 4;
    #pragma unroll 4
    for (int k = 0; k < CIN; k += 4) {
        vfloat4 b0 = *(const vfloat4*)(Wp + (size_t)(k + 0) * COUT);
        vfloat4 b1 = *(const vfloat4*)(Wp + (size_t)(k + 1) * COUT);
        vfloat4 b2 = *(const vfloat4*)(Wp + (size_t)(k + 2) * COUT);
        vfloat4 b3 = *(const vfloat4*)(Wp + (size_t)(k + 3) * COUT);
        #pragma unroll
        for (int i = 0; i < 4; ++i) {
            vfloat4 a = *(const vfloat4*)&xs[tn * 4 + i][k];   // ds_read_b128
            #pragma unroll
            for (int j = 0; j < 4; ++j)
                acc[i][j] += a[0] * b0[j] + a[1] * b1[j] + a[2] * b2[j] + a[3] * b3[j];
        }
    }

    #pragma unroll
    for (int i = 0; i < 4; ++i) {
        int node = base + tn * 4 + i;
        if (node >= N) continue;
        vushort4 hv;
        #pragma unroll
        for (int j = 0; j < 4; ++j) hv[j] = f2bf(acc[i][j]);
        *(vushort4*)(xwh + (size_t)node * COUT + tc * 4) = hv;
    }

    // ---- deg phase (same bucket) ----
    const int pbase = b * CAP;
    const int cnt   = min(bcur[b], CAP);
    for (int j = t; j < cnt; j += 256) {
        vint2 v = pk[pbase + j];
        atomicAdd(&ldeg[(v.x >> 20) & 63], __int_as_float(v.y));
    }
    __syncthreads();
    int node = base + t;
    if (t < 64 && node < N) dinv[node] = rsqrtf(SELF_LOOP_W + ldeg[t]);
}

// ---------------------------------------------------------------------------
// per-bucket: pk -> LDS counting-sort, then atomic-free per-node accumulation
// with QUARTER-WAVE pairing (R0-EXACT: the 27 us verified variant).
__global__ __launch_bounds__(512) void aggregate_kernel(const int* __restrict__ bcur,
                                                        const vint2* __restrict__ pk,
                                                        const float* __restrict__ dinv,
                                                        const unsigned short* __restrict__ xwh,
                                                        const float* __restrict__ bias,
                                                        float* __restrict__ out) {
    __shared__ int   rawx[CAP];      // raw: row | ln<<20
    __shared__ float rawn[CAP];      // raw: ew * dinv[row]
    __shared__ int   s_r[CAP];       // sorted: row
    __shared__ float s_n[CAP];       // sorted: norm
    __shared__ int   lhist[64], lofs[64], lcur[64];

    const int t    = threadIdx.x;
    const int lane = t & 63;
    const int wv   = t >> 6;          // 0..7
    const int b    = blockIdx.x;
    const int base = b * CAP;
    const int cnt  = min(bcur[b], CAP);

    if (t < 64) lhist[t] = 0;
    __syncthreads();

    // stage + histogram (coalesced pk read, 512 parallel dinv loads)
    for (int j = t; j < cnt; j += 512) {
        vint2 v = pk[base + j];
        rawx[j] = v.x;
        rawn[j] = __int_as_float(v.y) * dinv[v.x & 0xFFFFF];
        atomicAdd(&lhist[(v.x >> 20) & 63], 1);
    }
    __syncthreads();

    // wave 0: exclusive prefix scan of the 64 counters
    if (t < 64) {
        int v = lhist[t];
        int s = v;
        #pragma unroll
        for (int d = 1; d < 64; d <<= 1) {
            int u = __shfl_up(s, d);
            if (lane >= d) s += u;
        }
        lofs[t] = s - v;
        lcur[t] = s - v;
    }
    __syncthreads();

    // counting-sort scatter (LDS -> LDS)
    for (int j = t; j < cnt; j += 512) {
        int xv = rawx[j];
        int p  = atomicAdd(&lcur[(xv >> 20) & 63], 1);
        s_r[p] = xv & 0xFFFFF;
        s_n[p] = rawn[j];
    }
    __syncthreads();

    const int q  = lane >> 4;        // record quarter 0..3
    const int c4 = lane & 15;        // channel quad: channels c4*4 .. +3

    for (int nd = wv; nd < 64; nd += 8) {
        int node = b * 64 + nd;
        if (node >= N) continue;     // wave-uniform
        int s0 = lofs[nd];
        int e0 = s0 + lhist[nd];

        float a0 = 0.f, a1 = 0.f, a2 = 0.f, a3 = 0.f;
        for (int i = s0; i < e0; i += 16) {
            int rr[4]; float nn[4]; vushort4 vv[4];
            #pragma unroll
            for (int u = 0; u < 4; ++u) {
                int j = i + 4 * u + q;
                bool ok = (j < e0);
                rr[u] = ok ? s_r[j] : s_r[s0];
                nn[u] = ok ? s_n[j] : 0.f;
            }
            #pragma unroll
            for (int u = 0; u < 4; ++u)
                vv[u] = *(const vushort4*)(xwh + (size_t)rr[u] * COUT + c4 * 4);
            #pragma unroll
            for (int u = 0; u < 4; ++u) {
                a0 += nn[u] * bf2f(vv[u][0]);
                a1 += nn[u] * bf2f(vv[u][1]);
                a2 += nn[u] * bf2f(vv[u][2]);
                a3 += nn[u] * bf2f(vv[u][3]);
            }
        }
        // combine the four record-quarters
        a0 += __shfl_xor(a0, 16); a0 += __shfl_xor(a0, 32);
        a1 += __shfl_xor(a1, 16); a1 += __shfl_xor(a1, 32);
        a2 += __shfl_xor(a2, 16); a2 += __shfl_xor(a2, 32);
        a3 += __shfl_xor(a3, 16); a3 += __shfl_xor(a3, 32);

        if (q == 0) {                // lanes 0..15 write float4 (256B row)
            float dc = dinv[node];
            float s2 = SELF_LOOP_W * dc * dc;
            vushort4 sh = *(const vushort4*)(xwh + (size_t)node * COUT + c4 * 4);
            vfloat4  bv = *(const vfloat4*)(bias + c4 * 4);
            vfloat4  o;
            o[0] = dc * a0 + s2 * bf2f(sh[0]) + bv[0];
            o[1] = dc * a1 + s2 * bf2f(sh[1]) + bv[1];
            o[2] = dc * a2 + s2 * bf2f(sh[2]) + bv[2];
            o[3] = dc * a3 + s2 * bf2f(sh[3]) + bv[3];
            *(vfloat4*)(out + (size_t)node * COUT + c4 * 4) = o;
        }
    }
}

// ---------------------------------------------------------------------------
extern "C" void kernel_launch(void* const* d_in, const int* in_sizes, int n_in,
                              void* d_out, int out_size, void* d_ws, size_t ws_size,
                              hipStream_t stream) {
    const float* x  = (const float*)d_in[0];
    const int*   ei = (const int*)d_in[1];   // [2, E] int32
    const float* ew = (const float*)d_in[2];
    const float* W  = (const float*)d_in[3];
    const float* b  = (const float*)d_in[4];
    float* out = (float*)d_out;

    // ws layout
    unsigned short* xwh  = (unsigned short*)d_ws;            // N*COUT bf16 (6.4 MB)
    float*          dinv = (float*)(xwh + (size_t)N * COUT); // N
    int*            bcur = (int*)(dinv + N);                 // NB
    vint2*          pk   = (vint2*)(bcur + NB + 2);          // NB*CAP records (9.6 MB)

    const int* rowp = ei;
    const int* colp = ei + E;

    hipMemsetAsync(bcur, 0, NB * sizeof(int), stream);
    partition_kernel<<<PBLK, 512, 0, stream>>>(rowp, colp, ew, bcur, pk);
    xw_deg_kernel   <<<NB, 256, 0, stream>>>(x, W, bcur, pk, xwh, dinv);
    aggregate_kernel<<<NB, 512, 0, stream>>>(bcur, pk, dinv, xwh, b, out);
}